// Round 5
// baseline (825.486 us; speedup 1.0000x reference)
//
#include <hip/hip_runtime.h>
#include <hip/hip_bf16.h>

#define Bsz  16384
#define Din  1024
#define Dout 1024
#define Hdim 2048
#define Ecnt 8
#define CNT_PAD 32   // pad expert counters to 128 B apart

typedef _Float16 f16;
typedef _Float16 f16x8 __attribute__((ext_vector_type(8)));
typedef _Float16 f16x4 __attribute__((ext_vector_type(4)));
typedef float    f32x4 __attribute__((ext_vector_type(4)));

#define AS_GLOBAL __attribute__((address_space(1)))
#define AS_LDS    __attribute__((address_space(3)))

__device__ __forceinline__ void async_copy16(const void* gptr, void* lptr) {
    __builtin_amdgcn_global_load_lds(
        (const AS_GLOBAL unsigned int*)gptr,
        (AS_LDS unsigned int*)lptr, 16, 0, 0);
}

__device__ __forceinline__ void bar() {
    __builtin_amdgcn_s_barrier();
    asm volatile("" ::: "memory");   // pin LDS reads below the barrier
}

// ---------------- fp32 -> fp16 cast ----------------
__global__ __launch_bounds__(256) void cast_kernel(
    const float* __restrict__ in, f16* __restrict__ out)
{
    int i = (blockIdx.x * 256 + threadIdx.x) * 4;
    float4 v = *(const float4*)(in + i);
    f16x4 o;
    o.x = (f16)v.x; o.y = (f16)v.y; o.z = (f16)v.z; o.w = (f16)v.w;
    *(f16x4*)(out + i) = o;
}

// ---------------- Router: logits -> softmax -> top-2 -> buckets ----------------
__global__ __launch_bounds__(256) void router_kernel(
    const float* __restrict__ x, const float* __restrict__ rW,
    const float* __restrict__ rb, float* __restrict__ probs_out,
    int* __restrict__ cnt, int* __restrict__ bucket, float* __restrict__ gates)
{
    __shared__ float s_rw[Ecnt * Din];   // 32 KiB
    __shared__ int   s_e[64];
    __shared__ float s_g[64];
    __shared__ int   s_lpos[64];
    __shared__ int   s_lcnt[Ecnt];
    __shared__ int   s_base[Ecnt];

    int t = threadIdx.x;
    if (t < Ecnt) s_lcnt[t] = 0;
    for (int i = t; i < Ecnt * Din; i += 256) s_rw[i] = rW[i];
    __syncthreads();

    int wid = t >> 6, lane = t & 63;

    float rbv[8];
    #pragma unroll
    for (int e = 0; e < 8; e++) rbv[e] = rb[e];

    #pragma unroll 2
    for (int tt = 0; tt < 8; tt++) {
        int li = wid * 8 + tt;
        int token = blockIdx.x * 32 + li;
        const float* xrow = x + (size_t)token * Din;

        float acc[8] = {0,0,0,0,0,0,0,0};
        #pragma unroll
        for (int i = 0; i < 4; i++) {
            float4 xv = *(const float4*)(xrow + i * 256 + lane * 4);
            #pragma unroll
            for (int e = 0; e < 8; e++) {
                float4 wv = *(const float4*)(s_rw + e * Din + i * 256 + lane * 4);
                acc[e] += xv.x * wv.x + xv.y * wv.y + xv.z * wv.z + xv.w * wv.w;
            }
        }
        #pragma unroll
        for (int e = 0; e < 8; e++) {
            #pragma unroll
            for (int m = 1; m < 64; m <<= 1) acc[e] += __shfl_xor(acc[e], m, 64);
        }

        float p[8], mx = -1e30f;
        #pragma unroll
        for (int e = 0; e < 8; e++) { p[e] = acc[e] + rbv[e]; mx = fmaxf(mx, p[e]); }
        float s = 0.f;
        #pragma unroll
        for (int e = 0; e < 8; e++) { p[e] = expf(p[e] - mx); s += p[e]; }
        float inv = 1.f / s;
        #pragma unroll
        for (int e = 0; e < 8; e++) p[e] *= inv;

        if (lane == 0) {
            float* po = probs_out + (size_t)token * Ecnt;
            #pragma unroll
            for (int e = 0; e < 8; e++) po[e] = p[e];
            int i0 = 0; float v0 = p[0];
            #pragma unroll
            for (int e = 1; e < 8; e++) if (p[e] > v0) { v0 = p[e]; i0 = e; }
            int i1 = -1; float v1 = -1e30f;
            #pragma unroll
            for (int e = 0; e < 8; e++) if (e != i0 && p[e] > v1) { v1 = p[e]; i1 = e; }
            float invs = 1.f / (v0 + v1);
            s_e[2 * li]     = i0;  s_g[2 * li]     = v0 * invs;
            s_e[2 * li + 1] = i1;  s_g[2 * li + 1] = v1 * invs;
        }
    }
    __syncthreads();

    if (t < 64) s_lpos[t] = atomicAdd(&s_lcnt[s_e[t]], 1);
    __syncthreads();
    if (t < Ecnt) s_base[t] = atomicAdd(&cnt[t * CNT_PAD], s_lcnt[t]);
    __syncthreads();
    if (t < 64) {
        int e = s_e[t];
        int pos = s_base[e] + s_lpos[t];
        int li = t >> 1;
        int token = blockIdx.x * 32 + li;
        bucket[e * Bsz + pos] = token * 2 + (t & 1);
        gates [e * Bsz + pos] = s_g[t];
    }
}

// ---------------- MFMA grouped GEMM: 256x256, BK=64, deep-prefetch 8-phase ----------------
// R5 schedule (deepened vs R4): ALL 8 units of tile t+1 staged at P0 of tile t
// (issue order B0,B1,B2,B3,A0,A2,A1,A3 — A1/A3 LAST). Per-wave vmcnt ledger, steady state:
//   enter tile t: 2 outstanding (A1,A3 of t).
//   P0: +8 (tile t+1) -> 10.
//   end-P1: WAIT vmcnt(8) retires A1,A3(t)      [cover: issued (t-1)P0, 5 phases]
//           -> P2/P3 may read A-frags 4..7.
//   end-P3: WAIT vmcnt(2) retires B*4,A0,A2(t+1) [cover: issued (t)P0, 3 phases]
//           -> next tile P0/P1 reads valid. Invariant restored (2 outstanding).
// WAR safe: stage into buf nb at (t)P0; nb's last ds_reads were in (t-1)P3, completed
// before each wave's own lgkmcnt(0) there, published by (t-1)'s final barrier.
template<int Kd, bool G1>
__global__ __launch_bounds__(512, 2) void moe_gemm(
    const f16* __restrict__ A, const f16* __restrict__ Wt,
    const float* __restrict__ bias, const int* __restrict__ cnt,
    const int* __restrict__ bucket, const float* __restrict__ gates,
    f16* __restrict__ hbuf, float* __restrict__ out, int Ndim)
{
    // chunked XCD swizzle (bijective: gridDim.x % 8 == 0)
    int nblk = (int)gridDim.x;
    int lid = (int)blockIdx.x;
    lid = (lid & 7) * (nblk >> 3) + (lid >> 3);
    int gx = Ndim >> 8;
    int bx = lid % gx;
    int rem = lid / gx;
    int by = rem & 63;
    int e  = rem >> 6;

    int count = min(cnt[e * CNT_PAD], Bsz);
    int m0 = by * 256;
    if (m0 >= count) return;
    int n0 = bx * 256;

    __shared__ alignas(16) f16 lds[2 * 32768];   // 128 KiB: [buf][A 16K | B 16K] elems
    __shared__ int   s_rows[256];
    __shared__ float s_gates[256];

    int t = threadIdx.x;
    if (t < 256) {
        int pos = min(m0 + t, count - 1);
        s_rows[t] = bucket[e * Bsz + pos];
        if constexpr (!G1) s_gates[t] = gates[e * Bsz + pos];
    }
    __syncthreads();

    int wave = t >> 6, lane = t & 63;
    int wm = wave >> 2, wn = wave & 3;
    int frow = lane & 15;
    int fq   = lane >> 4;

    // staging: thread t covers (unit-row u*64 + (t>>3), 16B-chunk t&7); LDS dest linear,
    // global source pre-swizzled chunk c = (t&7) ^ (row&7)  (rule #21 both-sides)
    int srow = t >> 3;
    int sch  = t & 7;
    const f16* aGp[4];
    const f16* bGp[4];
    #pragma unroll
    for (int u = 0; u < 4; u++) {
        int trow = u * 64 + srow;
        int r = s_rows[trow];
        size_t arow = G1 ? (size_t)(r >> 1) : (size_t)r;
        int c = sch ^ (trow & 7);
        aGp[u] = A + arow * (size_t)Kd + c * 8;
        bGp[u] = Wt + ((size_t)e * Ndim + (n0 + trow)) * (size_t)Kd + c * 8;
    }

#define LDSA(b) (lds + (b) * 32768)
#define LDSB(b) (lds + (b) * 32768 + 16384)
#define STAGE_A(u, kk, b) async_copy16(aGp[u] + (kk), LDSA(b) + (u) * 4096 + wave * 512)
#define STAGE_B(u, kk, b) async_copy16(bGp[u] + (kk), LDSB(b) + (u) * 4096 + wave * 512)
#define WAIT_LGKM0 do { asm volatile("s_waitcnt lgkmcnt(0)" ::: "memory"); \
                        __builtin_amdgcn_sched_barrier(0); } while (0)
#define WAIT_VM(n) do { asm volatile("s_waitcnt vmcnt(" #n ")" ::: "memory"); \
                        __builtin_amdgcn_sched_barrier(0); } while (0)

    // fragment-read swizzled chunk offsets (row&7 == frow&7: row steps are multiples of 16)
    int sw0 = ((fq    ) ^ (frow & 7)) * 8;     // ks=0: logical chunk fq
    int sw1 = ((4 + fq) ^ (frow & 7)) * 8;     // ks=1: logical chunk 4+fq
    int aRowBase = (wm * 128 + frow) * 64;
    int bRowBase = (wn * 64  + frow) * 64;

    f32x4 acc[8][4] = {};
    f16x8 bf[4][2];
    f16x8 af[2][2];

    // prologue: stage tile 0 into buf 0 (order: B0..B3, A0, A2, then A1, A3 LAST)
    STAGE_B(0, 0, 0); STAGE_B(1, 0, 0); STAGE_B(2, 0, 0); STAGE_B(3, 0, 0);
    STAGE_A(0, 0, 0); STAGE_A(2, 0, 0); STAGE_A(1, 0, 0); STAGE_A(3, 0, 0);
    WAIT_VM(2);        // B + A0/A2 resident; A1/A3 in flight (= steady-state invariant)
    bar();

    const int NT = Kd / 64;
    for (int tt = 0; tt < NT; ++tt) {
        const int c  = tt & 1;
        const int nb = c ^ 1;
        const int kN = (tt + 1) * 64;
        const bool pf = (tt + 1 < NT);

        // ===== phase 0: stage ALL of tile t+1; read B(all) + A m-frags 0,1 =====
        if (pf) {
            STAGE_B(0, kN, nb); STAGE_B(1, kN, nb); STAGE_B(2, kN, nb); STAGE_B(3, kN, nb);
            STAGE_A(0, kN, nb); STAGE_A(2, kN, nb); STAGE_A(1, kN, nb); STAGE_A(3, kN, nb);
        }
        #pragma unroll
        for (int jj = 0; jj < 4; jj++) {
            bf[jj][0] = *(const f16x8*)(LDSB(c) + bRowBase + jj * 1024 + sw0);
            bf[jj][1] = *(const f16x8*)(LDSB(c) + bRowBase + jj * 1024 + sw1);
        }
        af[0][0] = *(const f16x8*)(LDSA(c) + aRowBase + 0 * 1024 + sw0);
        af[0][1] = *(const f16x8*)(LDSA(c) + aRowBase + 0 * 1024 + sw1);
        af[1][0] = *(const f16x8*)(LDSA(c) + aRowBase + 1 * 1024 + sw0);
        af[1][1] = *(const f16x8*)(LDSA(c) + aRowBase + 1 * 1024 + sw1);
        bar();
        WAIT_LGKM0;
        __builtin_amdgcn_s_setprio(1);
        #pragma unroll
        for (int jj = 0; jj < 4; jj++) {
            acc[0][jj] = __builtin_amdgcn_mfma_f32_16x16x32_f16(af[0][0], bf[jj][0], acc[0][jj], 0, 0, 0);
            acc[0][jj] = __builtin_amdgcn_mfma_f32_16x16x32_f16(af[0][1], bf[jj][1], acc[0][jj], 0, 0, 0);
            acc[1][jj] = __builtin_amdgcn_mfma_f32_16x16x32_f16(af[1][0], bf[jj][0], acc[1][jj], 0, 0, 0);
            acc[1][jj] = __builtin_amdgcn_mfma_f32_16x16x32_f16(af[1][1], bf[jj][1], acc[1][jj], 0, 0, 0);
        }
        __builtin_amdgcn_s_setprio(0);
        bar();

        // ===== phase 1: A m-frags 2,3 =====
        af[0][0] = *(const f16x8*)(LDSA(c) + aRowBase + 2 * 1024 + sw0);
        af[0][1] = *(const f16x8*)(LDSA(c) + aRowBase + 2 * 1024 + sw1);
        af[1][0] = *(const f16x8*)(LDSA(c) + aRowBase + 3 * 1024 + sw0);
        af[1][1] = *(const f16x8*)(LDSA(c) + aRowBase + 3 * 1024 + sw1);
        bar();
        WAIT_LGKM0;
        __builtin_amdgcn_s_setprio(1);
        #pragma unroll
        for (int jj = 0; jj < 4; jj++) {
            acc[2][jj] = __builtin_amdgcn_mfma_f32_16x16x32_f16(af[0][0], bf[jj][0], acc[2][jj], 0, 0, 0);
            acc[2][jj] = __builtin_amdgcn_mfma_f32_16x16x32_f16(af[0][1], bf[jj][1], acc[2][jj], 0, 0, 0);
            acc[3][jj] = __builtin_amdgcn_mfma_f32_16x16x32_f16(af[1][0], bf[jj][0], acc[3][jj], 0, 0, 0);
            acc[3][jj] = __builtin_amdgcn_mfma_f32_16x16x32_f16(af[1][1], bf[jj][1], acc[3][jj], 0, 0, 0);
        }
        __builtin_amdgcn_s_setprio(0);
        if (pf) { WAIT_VM(8); }   // retires A1,A3(cur) -> phases 2,3 may read frags 4..7
        else    { WAIT_VM(0); }
        bar();

        // ===== phase 2: A m-frags 4,5 =====
        af[0][0] = *(const f16x8*)(LDSA(c) + aRowBase + 4 * 1024 + sw0);
        af[0][1] = *(const f16x8*)(LDSA(c) + aRowBase + 4 * 1024 + sw1);
        af[1][0] = *(const f16x8*)(LDSA(c) + aRowBase + 5 * 1024 + sw0);
        af[1][1] = *(const f16x8*)(LDSA(c) + aRowBase + 5 * 1024 + sw1);
        bar();
        WAIT_LGKM0;
        __builtin_amdgcn_s_setprio(1);
        #pragma unroll
        for (int jj = 0; jj < 4; jj++) {
            acc[4][jj] = __builtin_amdgcn_mfma_f32_16x16x32_f16(af[0][0], bf[jj][0], acc[4][jj], 0, 0, 0);
            acc[4][jj] = __builtin_amdgcn_mfma_f32_16x16x32_f16(af[0][1], bf[jj][1], acc[4][jj], 0, 0, 0);
            acc[5][jj] = __builtin_amdgcn_mfma_f32_16x16x32_f16(af[1][0], bf[jj][0], acc[5][jj], 0, 0, 0);
            acc[5][jj] = __builtin_amdgcn_mfma_f32_16x16x32_f16(af[1][1], bf[jj][1], acc[5][jj], 0, 0, 0);
        }
        __builtin_amdgcn_s_setprio(0);
        bar();

        // ===== phase 3: A m-frags 6,7 =====
        af[0][0] = *(const f16x8*)(LDSA(c) + aRowBase + 6 * 1024 + sw0);
        af[0][1] = *(const f16x8*)(LDSA(c) + aRowBase + 6 * 1024 + sw1);
        af[1][0] = *(const f16x8*)(LDSA(c) + aRowBase + 7 * 1024 + sw0);
        af[1][1] = *(const f16x8*)(LDSA(c) + aRowBase + 7 * 1024 + sw1);
        bar();
        WAIT_LGKM0;
        __builtin_amdgcn_s_setprio(1);
        #pragma unroll
        for (int jj = 0; jj < 4; jj++) {
            acc[6][jj] = __builtin_amdgcn_mfma_f32_16x16x32_f16(af[0][0], bf[jj][0], acc[6][jj], 0, 0, 0);
            acc[6][jj] = __builtin_amdgcn_mfma_f32_16x16x32_f16(af[0][1], bf[jj][1], acc[6][jj], 0, 0, 0);
            acc[7][jj] = __builtin_amdgcn_mfma_f32_16x16x32_f16(af[1][0], bf[jj][0], acc[7][jj], 0, 0, 0);
            acc[7][jj] = __builtin_amdgcn_mfma_f32_16x16x32_f16(af[1][1], bf[jj][1], acc[7][jj], 0, 0, 0);
        }
        __builtin_amdgcn_s_setprio(0);
        if (pf) { WAIT_VM(2); }   // retires next tile's B + A0/A2 (3-phase cover); A1/A3 stay
        bar();
    }
#undef LDSA
#undef LDSB
#undef STAGE_A
#undef STAGE_B
#undef WAIT_LGKM0
#undef WAIT_VM

    // epilogue: D row m = wm*128 + i*16 + fq*4 + reg, col n = n0 + wn*64 + jj*16 + frow
    float bv[4];
    #pragma unroll
    for (int jj = 0; jj < 4; jj++)
        bv[jj] = bias[e * Ndim + n0 + wn * 64 + jj * 16 + frow];

    #pragma unroll
    for (int i = 0; i < 8; i++) {
        int mbase = wm * 128 + i * 16 + fq * 4;
        #pragma unroll
        for (int reg = 0; reg < 4; reg++) {
            int m = mbase + reg;
            if (m0 + m >= count) continue;
            int r = s_rows[m];
            if constexpr (G1) {
                f16* hrow = hbuf + (size_t)r * Hdim;
                #pragma unroll
                for (int jj = 0; jj < 4; jj++) {
                    int n = n0 + wn * 64 + jj * 16 + frow;
                    float v = acc[i][jj][reg] + bv[jj];
                    hrow[n] = (f16)fmaxf(v, 0.f);
                }
            } else {
                int token = r >> 1;
                float g = s_gates[m];
                #pragma unroll
                for (int jj = 0; jj < 4; jj++) {
                    int n = n0 + wn * 64 + jj * 16 + frow;
                    float v = g * (acc[i][jj][reg] + bv[jj]);
                    atomicAdd(&out[(size_t)token * Dout + n], v);
                }
            }
        }
    }
}

extern "C" void kernel_launch(void* const* d_in, const int* in_sizes, int n_in,
                              void* d_out, int out_size, void* d_ws, size_t ws_size,
                              hipStream_t stream) {
    const float* x   = (const float*)d_in[0];
    const float* rW  = (const float*)d_in[1];
    const float* rb  = (const float*)d_in[2];
    const float* W1  = (const float*)d_in[3];
    const float* b1  = (const float*)d_in[4];
    const float* W2  = (const float*)d_in[5];
    const float* b2  = (const float*)d_in[6];
    float* out   = (float*)d_out;
    float* probs = out + (size_t)Bsz * Dout;

    char* ws = (char*)d_ws;
    int*   cnt    = (int*)ws;                            // padded counters
    int*   bucket = (int*)(ws + 0x1000);                 // 512 KiB
    float* gates  = (float*)(ws + 0x90000);              // 512 KiB
    f16*   x16    = (f16*)(ws + 0x200000);               // 32 MiB
    f16*   w16    = (f16*)(ws + 0x2200000);              // 32 MiB (W1, then W2)
    f16*   hbuf   = (f16*)(ws + 0x4200000);              // 128 MiB

    hipMemsetAsync(cnt, 0, Ecnt * CNT_PAD * sizeof(int), stream);
    hipMemsetAsync(out, 0, (size_t)Bsz * Dout * sizeof(float), stream);

    cast_kernel<<<(Bsz * Din) / 1024, 256, 0, stream>>>(x, x16);
    cast_kernel<<<(Ecnt * Hdim * Din) / 1024, 256, 0, stream>>>(W1, w16);

    router_kernel<<<Bsz / 32, 256, 0, stream>>>(x, rW, rb, probs, cnt, bucket, gates);

    int nb1 = (Hdim / 256) * (Bsz / 256) * Ecnt;   // 4096, %8==0
    moe_gemm<Din, true><<<nb1, 512, 0, stream>>>(
        x16, w16, b1, cnt, bucket, gates, hbuf, out, Hdim);

    cast_kernel<<<(Ecnt * Dout * Hdim) / 1024, 256, 0, stream>>>(W2, w16);

    int nb2 = (Dout / 256) * (Bsz / 256) * Ecnt;   // 2048, %8==0
    moe_gemm<Hdim, false><<<nb2, 512, 0, stream>>>(
        hbuf, w16, b2, cnt, bucket, gates, hbuf, out, Dout);
}

// Round 6
// 681.615 us; speedup vs baseline: 1.2111x; 1.2111x over previous
//
#include <hip/hip_runtime.h>
#include <hip/hip_bf16.h>

#define Bsz  16384
#define Din  1024
#define Dout 1024
#define Hdim 2048
#define Ecnt 8
#define CNT_PAD 32   // pad expert counters to 128 B apart

typedef _Float16 f16;
typedef _Float16 f16x8 __attribute__((ext_vector_type(8)));
typedef _Float16 f16x4 __attribute__((ext_vector_type(4)));
typedef float    f32x4 __attribute__((ext_vector_type(4)));

#define AS_GLOBAL __attribute__((address_space(1)))
#define AS_LDS    __attribute__((address_space(3)))

__device__ __forceinline__ void async_copy16(const void* gptr, void* lptr) {
    __builtin_amdgcn_global_load_lds(
        (const AS_GLOBAL unsigned int*)gptr,
        (AS_LDS unsigned int*)lptr, 16, 0, 0);
}

// ---------------- fp32 -> fp16 cast ----------------
__global__ __launch_bounds__(256) void cast_kernel(
    const float* __restrict__ in, f16* __restrict__ out)
{
    int i = (blockIdx.x * 256 + threadIdx.x) * 4;
    float4 v = *(const float4*)(in + i);
    f16x4 o;
    o.x = (f16)v.x; o.y = (f16)v.y; o.z = (f16)v.z; o.w = (f16)v.w;
    *(f16x4*)(out + i) = o;
}

// ---------------- Router: logits -> softmax -> top-2 -> buckets ----------------
__global__ __launch_bounds__(256) void router_kernel(
    const float* __restrict__ x, const float* __restrict__ rW,
    const float* __restrict__ rb, float* __restrict__ probs_out,
    int* __restrict__ cnt, int* __restrict__ bucket, float* __restrict__ gates)
{
    __shared__ float s_rw[Ecnt * Din];   // 32 KiB
    __shared__ int   s_e[64];
    __shared__ float s_g[64];
    __shared__ int   s_lpos[64];
    __shared__ int   s_lcnt[Ecnt];
    __shared__ int   s_base[Ecnt];

    int t = threadIdx.x;
    if (t < Ecnt) s_lcnt[t] = 0;
    for (int i = t; i < Ecnt * Din; i += 256) s_rw[i] = rW[i];
    __syncthreads();

    int wid = t >> 6, lane = t & 63;

    float rbv[8];
    #pragma unroll
    for (int e = 0; e < 8; e++) rbv[e] = rb[e];

    #pragma unroll 2
    for (int tt = 0; tt < 8; tt++) {
        int li = wid * 8 + tt;
        int token = blockIdx.x * 32 + li;
        const float* xrow = x + (size_t)token * Din;

        float acc[8] = {0,0,0,0,0,0,0,0};
        #pragma unroll
        for (int i = 0; i < 4; i++) {
            float4 xv = *(const float4*)(xrow + i * 256 + lane * 4);
            #pragma unroll
            for (int e = 0; e < 8; e++) {
                float4 wv = *(const float4*)(s_rw + e * Din + i * 256 + lane * 4);
                acc[e] += xv.x * wv.x + xv.y * wv.y + xv.z * wv.z + xv.w * wv.w;
            }
        }
        #pragma unroll
        for (int e = 0; e < 8; e++) {
            #pragma unroll
            for (int m = 1; m < 64; m <<= 1) acc[e] += __shfl_xor(acc[e], m, 64);
        }

        float p[8], mx = -1e30f;
        #pragma unroll
        for (int e = 0; e < 8; e++) { p[e] = acc[e] + rbv[e]; mx = fmaxf(mx, p[e]); }
        float s = 0.f;
        #pragma unroll
        for (int e = 0; e < 8; e++) { p[e] = expf(p[e] - mx); s += p[e]; }
        float inv = 1.f / s;
        #pragma unroll
        for (int e = 0; e < 8; e++) p[e] *= inv;

        if (lane == 0) {
            float* po = probs_out + (size_t)token * Ecnt;
            #pragma unroll
            for (int e = 0; e < 8; e++) po[e] = p[e];
            int i0 = 0; float v0 = p[0];
            #pragma unroll
            for (int e = 1; e < 8; e++) if (p[e] > v0) { v0 = p[e]; i0 = e; }
            int i1 = -1; float v1 = -1e30f;
            #pragma unroll
            for (int e = 0; e < 8; e++) if (e != i0 && p[e] > v1) { v1 = p[e]; i1 = e; }
            float invs = 1.f / (v0 + v1);
            s_e[2 * li]     = i0;  s_g[2 * li]     = v0 * invs;
            s_e[2 * li + 1] = i1;  s_g[2 * li + 1] = v1 * invs;
        }
    }
    __syncthreads();

    if (t < 64) s_lpos[t] = atomicAdd(&s_lcnt[s_e[t]], 1);
    __syncthreads();
    if (t < Ecnt) s_base[t] = atomicAdd(&cnt[t * CNT_PAD], s_lcnt[t]);
    __syncthreads();
    if (t < 64) {
        int e = s_e[t];
        int pos = s_base[e] + s_lpos[t];
        int li = t >> 1;
        int token = blockIdx.x * 32 + li;
        bucket[e * Bsz + pos] = token * 2 + (t & 1);
        gates [e * Bsz + pos] = s_g[t];
    }
}

// ---------------- MFMA grouped GEMM (proven 128x128 2-phase dbuf, R2 structure) ----------------
// R6 change vs the 706us kernel: ONLY the grid mapping. 1-D grid, expert-major XCD map:
//   e = bid % 8  -> each XCD (assumed bid%8 round-robin) owns ONE expert; its W[e] in f16
//   is exactly 4 MiB = one XCD L2, becoming L2-resident.
//   idx = bid/8 enumerates (m-block, n-block) with n FASTEST -> the 8-16 blocks sharing a
//   gathered A-panel (512 KiB) run consecutively on the SAME XCD while the panel is L2-hot.
// Attacks the measured 550 MiB overfetch (ideal ~160 MiB) and swaps ~900cyc HBM latency
// for ~200cyc L2 latency in the per-K-step drain.
template<int Kd, bool G1>
__global__ __launch_bounds__(256) void moe_gemm(
    const f16* __restrict__ A, const f16* __restrict__ Wt,
    const float* __restrict__ bias, const int* __restrict__ cnt,
    const int* __restrict__ bucket, const float* __restrict__ gates,
    f16* __restrict__ hbuf, float* __restrict__ out, int Ndim)
{
    int e   = (int)blockIdx.x & 7;
    int idx = (int)blockIdx.x >> 3;
    int nx  = Ndim >> 7;               // n-blocks per expert (8 or 16, power of 2)
    int by  = idx / nx;                // m-block (n fastest for A-panel L2 reuse)
    int bx  = idx - by * nx;

    int count = min(cnt[e * CNT_PAD], Bsz);
    int m0 = by * 128;
    if (m0 >= count) return;
    int n0 = bx * 128;

    __shared__ alignas(16) f16 As[2][128 * 32];   // 2 x 8 KiB
    __shared__ alignas(16) f16 Bs[2][128 * 32];   // 2 x 8 KiB
    __shared__ int   s_rows[128];
    __shared__ float s_gates[128];

    int t = threadIdx.x;
    if (t < 128) {
        int pos = min(m0 + t, count - 1);
        s_rows[t] = bucket[e * Bsz + pos];
        if constexpr (!G1) s_gates[t] = gates[e * Bsz + pos];
    }
    __syncthreads();

    int wave = t >> 6, lane = t & 63;
    int scol = (lane & 3) * 8;            // f16 elems within row (16 B chunks)

    const f16* agp[2];
    const f16* bgp[2];
    #pragma unroll
    for (int j = 0; j < 2; j++) {
        int srow = wave * 32 + j * 16 + (lane >> 2);
        int r = s_rows[srow];
        size_t arow = G1 ? (size_t)(r >> 1) : (size_t)r;
        agp[j] = A + arow * Kd + scol;
        bgp[j] = Wt + ((size_t)e * Ndim + (n0 + srow)) * (size_t)Kd + scol;
    }

    int m_w = (wave >> 1) * 64;           // wave's 64x64 sub-tile
    int n_w = (wave & 1) * 64;
    int frow = lane & 15;
    int fk   = (lane >> 4) * 8;

    f32x4 acc[4][4] = {};

    // prologue: stage tile 0 into buffer 0
    #pragma unroll
    for (int j = 0; j < 2; j++) {
        async_copy16(agp[j], &As[0][(wave * 32 + j * 16) * 32]);
        async_copy16(bgp[j], &Bs[0][(wave * 32 + j * 16) * 32]);
        agp[j] += 32; bgp[j] += 32;
    }
    __syncthreads();   // vmcnt(0) drain: tile 0 resident

    int cur = 0;
    for (int k0 = 0; k0 < Kd; k0 += 32) {
        // 1) ds_reads of current buffer
        f16x8 af[4], bfr[4];
        #pragma unroll
        for (int i = 0; i < 4; i++) {
            af[i]  = *(const f16x8*)(&As[cur][(m_w + i * 16 + frow) * 32 + fk]);
            bfr[i] = *(const f16x8*)(&Bs[cur][(n_w + i * 16 + frow) * 32 + fk]);
        }
        // 2) prefetch next K-tile into the other buffer; latency hides under MFMA
        if (k0 + 32 < Kd) {
            #pragma unroll
            for (int j = 0; j < 2; j++) {
                async_copy16(agp[j], &As[cur ^ 1][(wave * 32 + j * 16) * 32]);
                async_copy16(bgp[j], &Bs[cur ^ 1][(wave * 32 + j * 16) * 32]);
                agp[j] += 32; bgp[j] += 32;
            }
        }
        // 3) MFMA
        __builtin_amdgcn_s_setprio(1);
        #pragma unroll
        for (int i = 0; i < 4; i++)
            #pragma unroll
            for (int jj = 0; jj < 4; jj++)
                acc[i][jj] = __builtin_amdgcn_mfma_f32_16x16x32_f16(
                    af[i], bfr[jj], acc[i][jj], 0, 0, 0);
        __builtin_amdgcn_s_setprio(0);
        // 4) single barrier per K-step
        __syncthreads();
        cur ^= 1;
    }

    // epilogue: D row = m = (lane>>4)*4 + reg (+16*i), D col = n = lane&15 (+16*jj)
    float bv[4];
    #pragma unroll
    for (int jj = 0; jj < 4; jj++)
        bv[jj] = bias[e * Ndim + n0 + n_w + jj * 16 + frow];

    #pragma unroll
    for (int i = 0; i < 4; i++) {
        int mbase = m_w + i * 16 + (lane >> 4) * 4;
        #pragma unroll
        for (int reg = 0; reg < 4; reg++) {
            int m = mbase + reg;
            if (m0 + m >= count) continue;
            int r = s_rows[m];
            if constexpr (G1) {
                f16* hrow = hbuf + (size_t)r * Hdim;
                #pragma unroll
                for (int jj = 0; jj < 4; jj++) {
                    int n = n0 + n_w + jj * 16 + frow;
                    float v = acc[i][jj][reg] + bv[jj];
                    hrow[n] = (f16)fmaxf(v, 0.f);
                }
            } else {
                int token = r >> 1;
                float g = s_gates[m];
                #pragma unroll
                for (int jj = 0; jj < 4; jj++) {
                    int n = n0 + n_w + jj * 16 + frow;
                    float v = g * (acc[i][jj][reg] + bv[jj]);
                    atomicAdd(&out[(size_t)token * Dout + n], v);
                }
            }
        }
    }
}

extern "C" void kernel_launch(void* const* d_in, const int* in_sizes, int n_in,
                              void* d_out, int out_size, void* d_ws, size_t ws_size,
                              hipStream_t stream) {
    const float* x   = (const float*)d_in[0];
    const float* rW  = (const float*)d_in[1];
    const float* rb  = (const float*)d_in[2];
    const float* W1  = (const float*)d_in[3];
    const float* b1  = (const float*)d_in[4];
    const float* W2  = (const float*)d_in[5];
    const float* b2  = (const float*)d_in[6];
    float* out   = (float*)d_out;
    float* probs = out + (size_t)Bsz * Dout;

    char* ws = (char*)d_ws;
    int*   cnt    = (int*)ws;                            // padded counters
    int*   bucket = (int*)(ws + 0x1000);                 // 512 KiB
    float* gates  = (float*)(ws + 0x90000);              // 512 KiB
    f16*   x16    = (f16*)(ws + 0x200000);               // 32 MiB
    f16*   w16    = (f16*)(ws + 0x2200000);              // 32 MiB (W1, then W2)
    f16*   hbuf   = (f16*)(ws + 0x4200000);              // 128 MiB

    hipMemsetAsync(cnt, 0, Ecnt * CNT_PAD * sizeof(int), stream);
    hipMemsetAsync(out, 0, (size_t)Bsz * Dout * sizeof(float), stream);

    cast_kernel<<<(Bsz * Din) / 1024, 256, 0, stream>>>(x, x16);
    cast_kernel<<<(Ecnt * Hdim * Din) / 1024, 256, 0, stream>>>(W1, w16);

    router_kernel<<<Bsz / 32, 256, 0, stream>>>(x, rW, rb, probs, cnt, bucket, gates);

    // expert-major 1-D grids: e = bid%8 (one expert per XCD), n-block fastest within expert
    int nb1 = Ecnt * (Bsz / 128) * (Hdim / 128);   // 16384
    moe_gemm<Din, true><<<nb1, 256, 0, stream>>>(
        x16, w16, b1, cnt, bucket, gates, hbuf, out, Hdim);

    cast_kernel<<<(Ecnt * Dout * Hdim) / 1024, 256, 0, stream>>>(W2, w16);

    int nb2 = Ecnt * (Bsz / 128) * (Dout / 128);   // 8192
    moe_gemm<Hdim, false><<<nb2, 256, 0, stream>>>(
        hbuf, w16, b2, cnt, bucket, gates, hbuf, out, Dout);
}